// Round 15
// baseline (603.605 us; speedup 1.0000x reference)
//
#include <hip/hip_runtime.h>
#include <hip/hip_bf16.h>
#include <hip/hip_fp16.h>
#include <cstdint>

#define HSZ    4194304ull   // B*H*S*Dh elements per head tensor
#define S_LEN  1024
#define NHEAD  16
#define DH     64

typedef __attribute__((ext_vector_type(8))) short bf16x8;
typedef __attribute__((ext_vector_type(8))) unsigned short u16x8;
typedef __attribute__((ext_vector_type(4))) unsigned short u16x4;
typedef __attribute__((ext_vector_type(4))) float f32x4;
#define MFMA(a,b,c) __builtin_amdgcn_mfma_f32_16x16x32_bf16(a,b,c,0,0,0)

__device__ __forceinline__ unsigned short f2bf(float f) {
    union { float f; uint32_t u; } v; v.f = f;
    uint32_t r = (v.u + 0x7fffu + ((v.u >> 16) & 1u)) >> 16;
    return (unsigned short)r;
}
__device__ __forceinline__ float bf2f(unsigned short u) {
    union { uint32_t u; float f; } v; v.u = (uint32_t)u << 16;
    return v.f;
}
__device__ __forceinline__ unsigned short f2h(float f) { return __half_as_ushort(__float2half(f)); }
__device__ __forceinline__ float h2f(unsigned short u) { return __half2float(__ushort_as_half(u)); }

// LDS-only barrier: waits LDS ops, NOT pending global (NT) stores.
__device__ __forceinline__ void bar_lds() {
    asm volatile("s_waitcnt lgkmcnt(0)" ::: "memory");
    __builtin_amdgcn_s_barrier();
}

// ======================= conv: X fp32 -> bf16 hi/lo =======================
__global__ __launch_bounds__(256) void conv_x_kernel(
    const float* __restrict__ X, unsigned short* __restrict__ xh, unsigned short* __restrict__ xl)
{
    const int idx = blockIdx.x * 256 + threadIdx.x;     // 524288
    float4 a = *(const float4*)&X[idx * 8];
    float4 b = *(const float4*)&X[idx * 8 + 4];
    float v[8] = {a.x, a.y, a.z, a.w, b.x, b.y, b.z, b.w};
    u16x8 hi, lo;
#pragma unroll
    for (int j = 0; j < 8; ++j) {
        unsigned short h = f2bf(v[j]);
        hi[j] = h;
        lo[j] = f2bf(v[j] - bf2f(h));
    }
    *(u16x8*)&xh[idx * 8] = hi;
    *(u16x8*)&xl[idx * 8] = lo;
}

// ======================= conv: weights fp32 -> bf16 (concat) =======================
// Wcat rows: [0,2048) wq, [2048,4096) wk, [4096,5120) wv, [5120,6144) wo
__global__ __launch_bounds__(256) void conv_w_kernel(
    const float* __restrict__ wq, const float* __restrict__ wk,
    const float* __restrict__ wv, const float* __restrict__ wo,
    unsigned short* __restrict__ Wcat)
{
    const int idx = blockIdx.x * 256 + threadIdx.x;     // 786432
    const int row = idx >> 7;
    const int cg  = idx & 127;
    const float* src;
    int rl;
    if (row < 2048)      { src = wq; rl = row; }
    else if (row < 4096) { src = wk; rl = row - 2048; }
    else if (row < 5120) { src = wv; rl = row - 4096; }
    else                 { src = wo; rl = row - 5120; }
    float4 a = *(const float4*)&src[(size_t)rl * 1024 + cg * 8];
    float4 b = *(const float4*)&src[(size_t)rl * 1024 + cg * 8 + 4];
    float v[8] = {a.x, a.y, a.z, a.w, b.x, b.y, b.z, b.w};
    u16x8 o;
#pragma unroll
    for (int j = 0; j < 8; ++j) o[j] = f2bf(v[j]);
    *(u16x8*)&Wcat[(size_t)row * 1024 + cg * 8] = o;
}

// ======================= conv: C mask fp32 -> bf16 =======================
__global__ __launch_bounds__(256) void conv_c_kernel(
    const float* __restrict__ C, unsigned short* __restrict__ Cb)
{
    const int idx = blockIdx.x * 256 + threadIdx.x;     // 131072
    float4 a = *(const float4*)&C[idx * 8];
    float4 b = *(const float4*)&C[idx * 8 + 4];
    float v[8] = {a.x, a.y, a.z, a.w, b.x, b.y, b.z, b.w};
    u16x8 o;
#pragma unroll
    for (int j = 0; j < 8; ++j) o[j] = f2bf(v[j]);
    *(u16x8*)&Cb[idx * 8] = o;
}

// ======================= projection GEMM (MFMA) + fused RoPE =======================
// qk layout: 0:q1h 1:q1l 2:q2h 3:q2l 4:k1 5:k2  (K single-bf16)
// X hi/lo split only for q tiles (n0<2048).
__global__ __launch_bounds__(256) void proj_mfma_kernel(
    const unsigned short* __restrict__ xh, const unsigned short* __restrict__ xl,
    const unsigned short* __restrict__ Wcat,
    const float* __restrict__ bq, const float* __restrict__ bk, const float* __restrict__ bv,
    unsigned short* __restrict__ qk, unsigned short* __restrict__ vt)
{
    __shared__ __align__(16) unsigned short Ah[128 * 64];
    __shared__ __align__(16) unsigned short Al[128 * 64];
    __shared__ __align__(16) unsigned short Bs[128 * 64];

    const int t   = threadIdx.x;
    const int bid = blockIdx.x;                 // 1280
    const int swz = (bid & 7) * 160 + (bid >> 3);
    const int n_idx = swz % 40, m_idx = swz / 40;
    const int m0 = m_idx * 128, n0 = n_idx * 128;
    const int w = t >> 6, l = t & 63, ln = l & 15, kg = l >> 4;
    const int wm = w >> 1, wn = w & 1;
    const bool useLo = (n0 < 2048);             // hi/lo only for q segment

    f32x4 acc[4][4];
#pragma unroll
    for (int i = 0; i < 4; ++i)
#pragma unroll
        for (int j = 0; j < 4; ++j) acc[i][j] = (f32x4){0.f, 0.f, 0.f, 0.f};

    for (int k0 = 0; k0 < 1024; k0 += 64) {
        __syncthreads();
#pragma unroll
        for (int i = 0; i < 4; ++i) {
            const int e   = t + i * 256;
            const int row = e >> 3, cg = e & 7;
            const int off = (row * 128 + cg * 16) ^ ((row & 7) << 4);
            const size_t ga = (size_t)(m0 + row) * 1024 + k0 + cg * 8;
            const size_t gb = (size_t)(n0 + row) * 1024 + k0 + cg * 8;
            *(bf16x8*)((char*)Ah + off) = *(const bf16x8*)(xh + ga);
            if (useLo)
                *(bf16x8*)((char*)Al + off) = *(const bf16x8*)(xl + ga);
            *(bf16x8*)((char*)Bs + off) = *(const bf16x8*)(Wcat + gb);
        }
        __syncthreads();
#pragma unroll
        for (int ks = 0; ks < 2; ++ks) {
            bf16x8 bfrag[4];
#pragma unroll
            for (int nj = 0; nj < 4; ++nj) {
                const int row = wn * 64 + nj * 16 + ln;
                const int off = (row * 128 + ks * 64 + kg * 16) ^ ((row & 7) << 4);
                bfrag[nj] = *(const bf16x8*)((const char*)Bs + off);
            }
#pragma unroll
            for (int mi = 0; mi < 4; ++mi) {
                const int row = wm * 64 + mi * 16 + ln;
                const int off = (row * 128 + ks * 64 + kg * 16) ^ ((row & 7) << 4);
                bf16x8 ah = *(const bf16x8*)((const char*)Ah + off);
#pragma unroll
                for (int nj = 0; nj < 4; ++nj)
                    acc[mi][nj] = MFMA(ah, bfrag[nj], acc[mi][nj]);
                if (useLo) {
                    bf16x8 al = *(const bf16x8*)((const char*)Al + off);
#pragma unroll
                    for (int nj = 0; nj < 4; ++nj)
                        acc[mi][nj] = MFMA(al, bfrag[nj], acc[mi][nj]);
                }
            }
        }
    }

    // epilogue: n0 block lies entirely in one segment (q/k/v)
    const int seg = (n0 < 2048) ? 0 : (n0 < 4096 ? 1 : 2);
    if (seg < 2) {
        const float* bias = (seg == 0) ? bq : bk;
#pragma unroll
        for (int njp = 0; njp < 2; ++njp) {
            const int n1  = n0 + wn * 64 + njp * 16 + ln;
            const int nl1 = n1 - seg * 2048;
            const int head = (nl1 >> 6) & 15;
            const int dd   = nl1 & 63;                  // < 32
            const float bb1 = bias[nl1];
            const float bb2 = bias[nl1 + 32];
            const float freq = exp2f((float)dd * (-13.287712379549449f / 32.0f));
            unsigned short* hiT;
            unsigned short* loT = nullptr;
            if (seg == 0) {   // q: hi/lo pair, tensors 0..3
                const int tq = (nl1 >> 10);
                hiT = qk + (size_t)(tq * 2)     * HSZ;
                loT = qk + (size_t)(tq * 2 + 1) * HSZ;
            } else {          // k: single bf16, tensors 4..5
                hiT = qk + (size_t)(4 + (nl1 >> 10)) * HSZ;
            }
#pragma unroll
            for (int mi = 0; mi < 4; ++mi) {
                const int mb = m0 + wm * 64 + mi * 16 + kg * 4;
#pragma unroll
                for (int r = 0; r < 4; ++r) {
                    const int m = mb + r, b_ = m >> 10, s = m & 1023;
                    float sn, cs;
                    sincosf((float)s * freq, &sn, &cs);
                    const float x1 = acc[mi][njp][r]     + bb1;
                    const float x2 = acc[mi][njp + 2][r] + bb2;
                    const float r1 = x1 * cs - x2 * sn;
                    const float r2 = x1 * sn + x2 * cs;
                    const size_t base = (((size_t)(b_ * 16 + head)) * 1024 + s) * 64;
                    const unsigned short h1 = f2bf(r1), h2 = f2bf(r2);
                    hiT[base + dd]      = h1;
                    hiT[base + dd + 32] = h2;
                    if (seg == 0) {
                        loT[base + dd]      = f2bf(r1 - bf2f(h1));
                        loT[base + dd + 32] = f2bf(r2 - bf2f(h2));
                    }
                }
            }
        }
    } else {
#pragma unroll
        for (int mi = 0; mi < 4; ++mi) {
#pragma unroll
            for (int nj = 0; nj < 4; ++nj) {
                const int n  = n0 + wn * 64 + nj * 16 + ln;
                const int nl = n - 4096;
                const float bb = bv[nl];
                const int head = nl >> 6, d = nl & 63;
                const int mb = m0 + wm * 64 + mi * 16 + kg * 4;
                const int b = mb >> 10, sb = mb & 1023;
                u16x4 o;
#pragma unroll
                for (int r = 0; r < 4; ++r) o[r] = f2bf(acc[mi][nj][r] + bb);
                *(u16x4*)(vt + ((size_t)(b * 16 + head) * 64 + d) * 1024 + sb) = o;
            }
        }
    }
}

// ======================= attention (MFMA) =======================
// 4096 blocks x 512 thr; block = one (bh, 16-row q-tile). XCD-swizzled.
// Wave-local-max softmax: phase A keeps 32 scores in regs, takes the per-wave
// row max m_w, stores e^(s-m_w) as f16 (<=1, safe) + per-wave partial sums.
// Phase B rebuilds the exact softmax: M=max_w m_w, cf_w=e^(m_w-M),
// sum=sum_w psum_w*cf_w. Deletes phase B's 64KB LDS re-exp sweep.
// (512,4): VGPR cap 128 -> scores in regs without scratch spill.
__global__ __launch_bounds__(512, 4) void attn_kernel(
    const unsigned short* __restrict__ qk,   // 6 tensors [bh][1024][64]
    const unsigned short* __restrict__ vt,   // [bh][64][1024]
    const unsigned short* __restrict__ Cb,   // bf16 [1024][1024]
    const int* __restrict__ pad,
    const float* __restrict__ lam_p,
    float* __restrict__ out_a1, float* __restrict__ out_a2,
    float* __restrict__ merged)
{
    __shared__ __align__(16) unsigned short sc[16][1032];   // 33 KB
    __shared__ __align__(16) float pmax[16][8];
    __shared__ __align__(16) float psum[16][8];
    __shared__ __align__(16) f32x4 red[256];                // 4 KB

    const int t  = threadIdx.x;
    const int w  = t >> 6;        // 0..7
    const int l  = t & 63;
    const int ln = l & 15;
    const int g  = l >> 4;
    const int kf = g * 8;

    const int flat = blockIdx.x;                       // 4096
    const int virt = (flat & 7) * 512 + (flat >> 3);   // XCD-contiguous bh
    const int bh = virt >> 6, b = bh >> 4, h = bh & 15;
    const int q0 = (virt & 63) * 16;
    const float lam = lam_p[0];

    const f32x4 Z = {0.f, 0.f, 0.f, 0.f};
    f32x4 ctx = Z;                 // persists across both passes
    const int dt  = w & 3;         // d-tile (phase C)
    const int khf = w >> 2;        // k-half (phase C)

    // pad bitmask: bit j = key (w*128 + j*16 + ln) valid. Reused across passes.
    uint32_t padm = 0;
#pragma unroll
    for (int j = 0; j < 8; ++j)
        padm |= (pad[b * S_LEN + w * 128 + j * 16 + ln] != 0 ? 1u : 0u) << j;

    for (int p = 0; p < 2; ++p) {
        const unsigned short* Qh = qk + (size_t)(2*p)     * HSZ + (size_t)bh * 65536;
        const unsigned short* Ql = qk + (size_t)(2*p + 1) * HSZ + (size_t)bh * 65536;
        const unsigned short* K  = qk + (size_t)(4 + p)   * HSZ + (size_t)bh * 65536;

        const size_t qb = (size_t)(q0 + ln) * 64 + kf;
        const bf16x8 qh0 = *(const bf16x8*)(Qh + qb);
        const bf16x8 qh1 = *(const bf16x8*)(Qh + qb + 32);
        const bf16x8 ql0 = *(const bf16x8*)(Ql + qb);
        const bf16x8 ql1 = *(const bf16x8*)(Ql + qb + 32);

        bar_lds();   // previous pass's PV reads of sc are complete (LDS-only)

        // ---- phase A: scores in regs, wave-local row max, exp, f16 store ----
        f32x4 s[8];
        f32x4 m = {-3.4e38f, -3.4e38f, -3.4e38f, -3.4e38f};
#pragma unroll 4
        for (int j = 0; j < 8; ++j) {
            const int key = w * 128 + j * 16 + ln;
            const size_t kb = (size_t)key * 64 + kf;
            const bf16x8 k0 = *(const bf16x8*)(K + kb);
            const bf16x8 k1 = *(const bf16x8*)(K + kb + 32);
            f32x4 a = Z;
            a = MFMA(qh0, k0, a); a = MFMA(qh1, k1, a);
            a = MFMA(ql0, k0, a); a = MFMA(ql1, k1, a);
            const bool ok = (padm >> j) & 1;
            const float mm = ok ? 0.125f : 0.0f;
            const float ma = ok ? 0.0f : -60000.0f;
#pragma unroll
            for (int r = 0; r < 4; ++r) {
                const float sv = a[r] * mm + ma;
                m[r] = fmaxf(m[r], sv);
                a[r] = sv;
            }
            s[j] = a;
        }
#pragma unroll
        for (int off = 1; off < 16; off <<= 1)
#pragma unroll
            for (int r = 0; r < 4; ++r) m[r] = fmaxf(m[r], __shfl_xor(m[r], off));
        // exp with wave-local max; store f16 exp + accumulate partial sums
        f32x4 ps = Z;
#pragma unroll
        for (int j = 0; j < 8; ++j) {
            const int key = w * 128 + j * 16 + ln;
#pragma unroll
            for (int r = 0; r < 4; ++r) {
                const float e = __expf(s[j][r] - m[r]);
                ps[r] += e;
                sc[g * 4 + r][key] = f2h(e);
            }
        }
#pragma unroll
        for (int off = 1; off < 16; off <<= 1)
#pragma unroll
            for (int r = 0; r < 4; ++r) ps[r] += __shfl_xor(ps[r], off);
        if (ln == 0) {
#pragma unroll
            for (int r = 0; r < 4; ++r) {
                pmax[g * 4 + r][w] = m[r];
                psum[g * 4 + r][w] = ps[r];
            }
        }
        bar_lds();

        // ---- phase B: rebuild global softmax, write a_p (NT) + combined ----
        {
            const int row = t >> 5, ci = t & 31;
            float M = pmax[row][0];
#pragma unroll
            for (int wi = 1; wi < 8; ++wi) M = fmaxf(M, pmax[row][wi]);
            float cf[8];
            float sum = 0.f;
#pragma unroll
            for (int wi = 0; wi < 8; ++wi) {
                cf[wi] = __expf(pmax[row][wi] - M);
                sum += psum[row][wi] * cf[wi];
            }
            const float inv = 1.0f / sum;
            const float fac = p ? -lam : 1.0f;
            float* aout = (p ? out_a2 : out_a1) + ((size_t)bh * S_LEN + q0 + row) * S_LEN;
            const unsigned short* Crow = Cb + (size_t)(q0 + row) * S_LEN;
#pragma unroll
            for (int it = 0; it < 4; ++it) {
                const int c0 = ci * 8 + it * 256;
                const int chunk = (ci >> 4) + it * 2;     // c0 >> 7
                const float cfi = cf[chunk] * inv;
                const u16x8 ev = *(const u16x8*)&sc[row][c0];
                const u16x8 cv = *(const u16x8*)&Crow[c0];
                float av[8];
#pragma unroll
                for (int i = 0; i < 8; ++i) av[i] = h2f(ev[i]) * cfi;
                f32x4 oa = {av[0], av[1], av[2], av[3]};
                f32x4 ob = {av[4], av[5], av[6], av[7]};
                __builtin_nontemporal_store(oa, (f32x4*)&aout[c0]);
                __builtin_nontemporal_store(ob, (f32x4*)&aout[c0 + 4]);
                u16x8 cw;
#pragma unroll
                for (int i = 0; i < 8; ++i) cw[i] = f2bf(bf2f(cv[i]) * av[i] * fac);
                *(u16x8*)&sc[row][c0] = cw;
            }
        }
        bar_lds();

        // ---- phase C: ctx += combined @ V ; wave = (dt, khf) ----
        {
            const unsigned short* vtb = vt + (size_t)bh * 65536
                                           + (size_t)(dt * 16 + ln) * S_LEN + kf;
#pragma unroll 8
            for (int ks = 0; ks < 16; ++ks) {
                const int kk = khf * 16 + ks;
                const bf16x8 A0 = *(const bf16x8*)&sc[ln][kk * 32 + kf];
                const bf16x8 Bv = *(const bf16x8*)(vtb + kk * 32);
                ctx = MFMA(A0, Bv, ctx);
            }
        }
    }

    // ---- cross-khf reduction + merged store ----
    __syncthreads();
    if (khf == 1) red[dt * 64 + l] = ctx;
    __syncthreads();
    if (khf == 0) {
        ctx += red[dt * 64 + l];
        const int col = h * DH + dt * 16 + ln;
#pragma unroll
        for (int r = 0; r < 4; ++r)
            merged[(size_t)(b * S_LEN + q0 + g * 4 + r) * 1024 + col] = ctx[r];
    }
}

// ======================= group-norm stats =======================
__global__ __launch_bounds__(256) void stats_kernel(
    const float* __restrict__ merged, float* __restrict__ stats)
{
    const int g = blockIdx.x;
    const int b = g >> 4, h = g & 15;
    const int t = threadIdx.x;
    float sum = 0.f, sq = 0.f;
    for (int i = t; i < 65536; i += 256) {
        const int s = i >> 6, d = i & 63;
        const float v = merged[((size_t)(b * S_LEN + s)) * 1024 + h * DH + d];
        sum += v; sq += v * v;
    }
#pragma unroll
    for (int off = 32; off > 0; off >>= 1) {
        sum += __shfl_xor(sum, off);
        sq  += __shfl_xor(sq, off);
    }
    __shared__ float rs[4], rq[4];
    const int wid = t >> 6;
    if ((t & 63) == 0) { rs[wid] = sum; rq[wid] = sq; }
    __syncthreads();
    if (t == 0) {
        const float S = rs[0] + rs[1] + rs[2] + rs[3];
        const float Q = rq[0] + rq[1] + rq[2] + rq[3];
        const float mean = S * (1.0f / 65536.0f);
        const float var  = Q * (1.0f / 65536.0f) - mean * mean;
        stats[2*g]   = mean;
        stats[2*g+1] = rsqrtf(var + 1e-5f);
    }
}

// ======================= groupnorm apply -> bf16 =======================
__global__ __launch_bounds__(256) void norm_conv_kernel(
    const float* __restrict__ merged, const float* __restrict__ stats,
    const float* __restrict__ gw, const float* __restrict__ gb,
    unsigned short* __restrict__ normed)
{
    const int idx = blockIdx.x * 256 + threadIdx.x;   // 524288
    const int m = idx >> 7;
    const int col8 = (idx & 127) * 8;
    const int b = m >> 10, h = col8 >> 6;
    const float mean = stats[2 * (b * 16 + h)];
    const float inv  = stats[2 * (b * 16 + h) + 1];
    float4 v0 = *(const float4*)&merged[(size_t)m * 1024 + col8];
    float4 v1 = *(const float4*)&merged[(size_t)m * 1024 + col8 + 4];
    float4 w0 = *(const float4*)&gw[col8];
    float4 w1 = *(const float4*)&gw[col8 + 4];
    float4 g0 = *(const float4*)&gb[col8];
    float4 g1 = *(const float4*)&gb[col8 + 4];
    float v[8] = {v0.x, v0.y, v0.z, v0.w, v1.x, v1.y, v1.z, v1.w};
    float wv[8] = {w0.x, w0.y, w0.z, w0.w, w1.x, w1.y, w1.z, w1.w};
    float gv[8] = {g0.x, g0.y, g0.z, g0.w, g1.x, g1.y, g1.z, g1.w};
    u16x8 o;
#pragma unroll
    for (int j = 0; j < 8; ++j)
        o[j] = f2bf(((v[j] - mean) * inv * wv[j] + gv[j]) * 0.2f);
    *(u16x8*)&normed[(size_t)m * 1024 + col8] = o;
}

// ======================= output GEMM (MFMA, single bf16) =======================
__global__ __launch_bounds__(256) void out_mfma_kernel(
    const unsigned short* __restrict__ An, const unsigned short* __restrict__ Wo_bf,
    const float* __restrict__ bo, float* __restrict__ out)
{
    __shared__ __align__(16) unsigned short As[128 * 64];
    __shared__ __align__(16) unsigned short Bs[128 * 64];

    const int t   = threadIdx.x;
    const int bid = blockIdx.x;                 // 256
    const int swz = (bid & 7) * 32 + (bid >> 3);
    const int n_idx = swz & 7, m_idx = swz >> 3;
    const int m0 = m_idx * 128, n0 = n_idx * 128;
    const int w = t >> 6, l = t & 63, ln = l & 15, kg = l >> 4;
    const int wm = w >> 1, wn = w & 1;

    f32x4 acc[4][4];
#pragma unroll
    for (int i = 0; i < 4; ++i)
#pragma unroll
        for (int j = 0; j < 4; ++j) acc[i][j] = (f32x4){0.f, 0.f, 0.f, 0.f};

    for (int k0 = 0; k0 < 1024; k0 += 64) {
        __syncthreads();
#pragma unroll
        for (int i = 0; i < 4; ++i) {
            const int e   = t + i * 256;
            const int row = e >> 3, cg = e & 7;
            const int off = (row * 128 + cg * 16) ^ ((row & 7) << 4);
            *(bf16x8*)((char*)As + off) = *(const bf16x8*)(An + (size_t)(m0 + row) * 1024 + k0 + cg * 8);
            *(bf16x8*)((char*)Bs + off) = *(const bf16x8*)(Wo_bf + (size_t)(n0 + row) * 1024 + k0 + cg * 8);
        }
        __syncthreads();
#pragma unroll
        for (int ks = 0; ks < 2; ++ks) {
            bf16x8 bfrag[4];
#pragma unroll
            for (int nj = 0; nj < 4; ++nj) {
                const int row = wn * 64 + nj * 16 + ln;
                const int off = (row * 128 + ks * 64 + kg * 16) ^ ((row & 7) << 4);
                bfrag[nj] = *(const bf16x8*)((const char*)Bs + off);
            }
#pragma unroll
            for (int mi = 0; mi < 4; ++mi) {
                const int row = wm * 64 + mi * 16 + ln;
                const int off = (row * 128 + ks * 64 + kg * 16) ^ ((row & 7) << 4);
                bf16x8 af = *(const bf16x8*)((const char*)As + off);
#pragma unroll
                for (int nj = 0; nj < 4; ++nj)
                    acc[mi][nj] = MFMA(af, bfrag[nj], acc[mi][nj]);
            }
        }
    }

#pragma unroll
    for (int mi = 0; mi < 4; ++mi) {
#pragma unroll
        for (int nj = 0; nj < 4; ++nj) {
            const int n = n0 + wn * 64 + nj * 16 + ln;
            const float bb = bo[n];
            const int mb = m0 + wm * 64 + mi * 16 + kg * 4;
#pragma unroll
            for (int r = 0; r < 4; ++r)
                out[(size_t)(mb + r) * 1024 + n] = acc[mi][nj][r] + bb;
        }
    }
}

// ======================= launcher =======================
extern "C" void kernel_launch(void* const* d_in, const int* in_sizes, int n_in,
                              void* d_out, int out_size, void* d_ws, size_t ws_size,
                              hipStream_t stream)
{
    const float* x   = (const float*)d_in[0];
    const float* lam = (const float*)d_in[1];
    const float* C   = (const float*)d_in[2];
    const int*   pad = (const int*)  d_in[3];
    const float* wq  = (const float*)d_in[4];
    const float* bq  = (const float*)d_in[5];
    const float* wk  = (const float*)d_in[6];
    const float* bk  = (const float*)d_in[7];
    const float* wv  = (const float*)d_in[8];
    const float* bv  = (const float*)d_in[9];
    const float* wo  = (const float*)d_in[10];
    const float* bo  = (const float*)d_in[11];
    const float* gw  = (const float*)d_in[12];
    const float* gb  = (const float*)d_in[13];

    float* out = (float*)d_out;
    float* a1  = out + 4194304;
    float* a2  = a1 + 67108864;

    unsigned short* xh   = (unsigned short*)d_ws;              // HSZ bf16 (dead after proj)
    unsigned short* xl   = xh + HSZ;                           // HSZ bf16 (dead after proj)
    unsigned short* qk   = xl + HSZ;                           // 6*HSZ bf16
    unsigned short* vt   = qk + 6 * HSZ;                       // HSZ bf16
    unsigned short* Wcat = vt + HSZ;                           // 6144*1024 bf16
    float* merged        = (float*)(Wcat + 6144ull * 1024);    // HSZ fp32
    float* stats         = merged + HSZ;                       // 128 fp32
    unsigned short* normed = (unsigned short*)(stats + 128);   // HSZ bf16
    unsigned short* Cb   = xh;                                 // alias: 1M bf16 in dead xh region

    conv_x_kernel<<<2048, 256, 0, stream>>>(x, xh, xl);
    conv_w_kernel<<<3072, 256, 0, stream>>>(wq, wk, wv, wo, Wcat);
    proj_mfma_kernel<<<1280, 256, 0, stream>>>(xh, xl, Wcat, bq, bk, bv, qk, vt);
    conv_c_kernel<<<512, 256, 0, stream>>>(C, Cb);
    attn_kernel<<<4096, 512, 0, stream>>>(qk, vt, Cb, pad, lam, a1, a2, merged);
    stats_kernel<<<64, 256, 0, stream>>>(merged, stats);
    norm_conv_kernel<<<2048, 256, 0, stream>>>(merged, stats, gw, gb, normed);
    out_mfma_kernel<<<256, 256, 0, stream>>>(normed, Wcat + 5120ull * 1024, bo, out);
}

// Round 16
// 527.592 us; speedup vs baseline: 1.1441x; 1.1441x over previous
//
#include <hip/hip_runtime.h>
#include <hip/hip_bf16.h>
#include <hip/hip_fp16.h>
#include <cstdint>

#define HSZ    4194304ull   // B*H*S*Dh elements per head tensor
#define S_LEN  1024
#define NHEAD  16
#define DH     64

typedef __attribute__((ext_vector_type(8))) short bf16x8;
typedef __attribute__((ext_vector_type(8))) unsigned short u16x8;
typedef __attribute__((ext_vector_type(4))) unsigned short u16x4;
typedef __attribute__((ext_vector_type(4))) float f32x4;
#define MFMA(a,b,c) __builtin_amdgcn_mfma_f32_16x16x32_bf16(a,b,c,0,0,0)

__device__ __forceinline__ unsigned short f2bf(float f) {
    union { float f; uint32_t u; } v; v.f = f;
    uint32_t r = (v.u + 0x7fffu + ((v.u >> 16) & 1u)) >> 16;
    return (unsigned short)r;
}
__device__ __forceinline__ float bf2f(unsigned short u) {
    union { uint32_t u; float f; } v; v.u = (uint32_t)u << 16;
    return v.f;
}
__device__ __forceinline__ unsigned short f2h(float f) { return __half_as_ushort(__float2half(f)); }
__device__ __forceinline__ float h2f(unsigned short u) { return __half2float(__ushort_as_half(u)); }

// LDS-only barrier: waits LDS ops, NOT pending global (NT) stores.
__device__ __forceinline__ void bar_lds() {
    asm volatile("s_waitcnt lgkmcnt(0)" ::: "memory");
    __builtin_amdgcn_s_barrier();
}

// ======================= conv: X fp32 -> bf16 hi/lo =======================
__global__ __launch_bounds__(256) void conv_x_kernel(
    const float* __restrict__ X, unsigned short* __restrict__ xh, unsigned short* __restrict__ xl)
{
    const int idx = blockIdx.x * 256 + threadIdx.x;     // 524288
    float4 a = *(const float4*)&X[idx * 8];
    float4 b = *(const float4*)&X[idx * 8 + 4];
    float v[8] = {a.x, a.y, a.z, a.w, b.x, b.y, b.z, b.w};
    u16x8 hi, lo;
#pragma unroll
    for (int j = 0; j < 8; ++j) {
        unsigned short h = f2bf(v[j]);
        hi[j] = h;
        lo[j] = f2bf(v[j] - bf2f(h));
    }
    *(u16x8*)&xh[idx * 8] = hi;
    *(u16x8*)&xl[idx * 8] = lo;
}

// ======================= conv: weights fp32 -> bf16 (concat) =======================
// Wcat rows: [0,2048) wq, [2048,4096) wk, [4096,5120) wv, [5120,6144) wo
__global__ __launch_bounds__(256) void conv_w_kernel(
    const float* __restrict__ wq, const float* __restrict__ wk,
    const float* __restrict__ wv, const float* __restrict__ wo,
    unsigned short* __restrict__ Wcat)
{
    const int idx = blockIdx.x * 256 + threadIdx.x;     // 786432
    const int row = idx >> 7;
    const int cg  = idx & 127;
    const float* src;
    int rl;
    if (row < 2048)      { src = wq; rl = row; }
    else if (row < 4096) { src = wk; rl = row - 2048; }
    else if (row < 5120) { src = wv; rl = row - 4096; }
    else                 { src = wo; rl = row - 5120; }
    float4 a = *(const float4*)&src[(size_t)rl * 1024 + cg * 8];
    float4 b = *(const float4*)&src[(size_t)rl * 1024 + cg * 8 + 4];
    float v[8] = {a.x, a.y, a.z, a.w, b.x, b.y, b.z, b.w};
    u16x8 o;
#pragma unroll
    for (int j = 0; j < 8; ++j) o[j] = f2bf(v[j]);
    *(u16x8*)&Wcat[(size_t)row * 1024 + cg * 8] = o;
}

// ======================= conv: C mask fp32 -> bf16 =======================
__global__ __launch_bounds__(256) void conv_c_kernel(
    const float* __restrict__ C, unsigned short* __restrict__ Cb)
{
    const int idx = blockIdx.x * 256 + threadIdx.x;     // 131072
    float4 a = *(const float4*)&C[idx * 8];
    float4 b = *(const float4*)&C[idx * 8 + 4];
    float v[8] = {a.x, a.y, a.z, a.w, b.x, b.y, b.z, b.w};
    u16x8 o;
#pragma unroll
    for (int j = 0; j < 8; ++j) o[j] = f2bf(v[j]);
    *(u16x8*)&Cb[idx * 8] = o;
}

// ======================= projection GEMM (MFMA) + fused RoPE =======================
// qk layout: 0:q1h 1:q1l 2:q2h 3:q2l 4:k1 5:k2  (K single-bf16)
// X hi/lo split only for q tiles (n0<2048).
__global__ __launch_bounds__(256) void proj_mfma_kernel(
    const unsigned short* __restrict__ xh, const unsigned short* __restrict__ xl,
    const unsigned short* __restrict__ Wcat,
    const float* __restrict__ bq, const float* __restrict__ bk, const float* __restrict__ bv,
    unsigned short* __restrict__ qk, unsigned short* __restrict__ vt)
{
    __shared__ __align__(16) unsigned short Ah[128 * 64];
    __shared__ __align__(16) unsigned short Al[128 * 64];
    __shared__ __align__(16) unsigned short Bs[128 * 64];

    const int t   = threadIdx.x;
    const int bid = blockIdx.x;                 // 1280
    const int swz = (bid & 7) * 160 + (bid >> 3);
    const int n_idx = swz % 40, m_idx = swz / 40;
    const int m0 = m_idx * 128, n0 = n_idx * 128;
    const int w = t >> 6, l = t & 63, ln = l & 15, kg = l >> 4;
    const int wm = w >> 1, wn = w & 1;
    const bool useLo = (n0 < 2048);             // hi/lo only for q segment

    f32x4 acc[4][4];
#pragma unroll
    for (int i = 0; i < 4; ++i)
#pragma unroll
        for (int j = 0; j < 4; ++j) acc[i][j] = (f32x4){0.f, 0.f, 0.f, 0.f};

    for (int k0 = 0; k0 < 1024; k0 += 64) {
        __syncthreads();
#pragma unroll
        for (int i = 0; i < 4; ++i) {
            const int e   = t + i * 256;
            const int row = e >> 3, cg = e & 7;
            const int off = (row * 128 + cg * 16) ^ ((row & 7) << 4);
            const size_t ga = (size_t)(m0 + row) * 1024 + k0 + cg * 8;
            const size_t gb = (size_t)(n0 + row) * 1024 + k0 + cg * 8;
            *(bf16x8*)((char*)Ah + off) = *(const bf16x8*)(xh + ga);
            if (useLo)
                *(bf16x8*)((char*)Al + off) = *(const bf16x8*)(xl + ga);
            *(bf16x8*)((char*)Bs + off) = *(const bf16x8*)(Wcat + gb);
        }
        __syncthreads();
#pragma unroll
        for (int ks = 0; ks < 2; ++ks) {
            bf16x8 bfrag[4];
#pragma unroll
            for (int nj = 0; nj < 4; ++nj) {
                const int row = wn * 64 + nj * 16 + ln;
                const int off = (row * 128 + ks * 64 + kg * 16) ^ ((row & 7) << 4);
                bfrag[nj] = *(const bf16x8*)((const char*)Bs + off);
            }
#pragma unroll
            for (int mi = 0; mi < 4; ++mi) {
                const int row = wm * 64 + mi * 16 + ln;
                const int off = (row * 128 + ks * 64 + kg * 16) ^ ((row & 7) << 4);
                bf16x8 ah = *(const bf16x8*)((const char*)Ah + off);
#pragma unroll
                for (int nj = 0; nj < 4; ++nj)
                    acc[mi][nj] = MFMA(ah, bfrag[nj], acc[mi][nj]);
                if (useLo) {
                    bf16x8 al = *(const bf16x8*)((const char*)Al + off);
#pragma unroll
                    for (int nj = 0; nj < 4; ++nj)
                        acc[mi][nj] = MFMA(al, bfrag[nj], acc[mi][nj]);
                }
            }
        }
    }

    // epilogue: n0 block lies entirely in one segment (q/k/v)
    const int seg = (n0 < 2048) ? 0 : (n0 < 4096 ? 1 : 2);
    if (seg < 2) {
        const float* bias = (seg == 0) ? bq : bk;
#pragma unroll
        for (int njp = 0; njp < 2; ++njp) {
            const int n1  = n0 + wn * 64 + njp * 16 + ln;
            const int nl1 = n1 - seg * 2048;
            const int head = (nl1 >> 6) & 15;
            const int dd   = nl1 & 63;                  // < 32
            const float bb1 = bias[nl1];
            const float bb2 = bias[nl1 + 32];
            const float freq = exp2f((float)dd * (-13.287712379549449f / 32.0f));
            unsigned short* hiT;
            unsigned short* loT = nullptr;
            if (seg == 0) {   // q: hi/lo pair, tensors 0..3
                const int tq = (nl1 >> 10);
                hiT = qk + (size_t)(tq * 2)     * HSZ;
                loT = qk + (size_t)(tq * 2 + 1) * HSZ;
            } else {          // k: single bf16, tensors 4..5
                hiT = qk + (size_t)(4 + (nl1 >> 10)) * HSZ;
            }
#pragma unroll
            for (int mi = 0; mi < 4; ++mi) {
                const int mb = m0 + wm * 64 + mi * 16 + kg * 4;
#pragma unroll
                for (int r = 0; r < 4; ++r) {
                    const int m = mb + r, b_ = m >> 10, s = m & 1023;
                    float sn, cs;
                    sincosf((float)s * freq, &sn, &cs);
                    const float x1 = acc[mi][njp][r]     + bb1;
                    const float x2 = acc[mi][njp + 2][r] + bb2;
                    const float r1 = x1 * cs - x2 * sn;
                    const float r2 = x1 * sn + x2 * cs;
                    const size_t base = (((size_t)(b_ * 16 + head)) * 1024 + s) * 64;
                    const unsigned short h1 = f2bf(r1), h2 = f2bf(r2);
                    hiT[base + dd]      = h1;
                    hiT[base + dd + 32] = h2;
                    if (seg == 0) {
                        loT[base + dd]      = f2bf(r1 - bf2f(h1));
                        loT[base + dd + 32] = f2bf(r2 - bf2f(h2));
                    }
                }
            }
        }
    } else {
#pragma unroll
        for (int mi = 0; mi < 4; ++mi) {
#pragma unroll
            for (int nj = 0; nj < 4; ++nj) {
                const int n  = n0 + wn * 64 + nj * 16 + ln;
                const int nl = n - 4096;
                const float bb = bv[nl];
                const int head = nl >> 6, d = nl & 63;
                const int mb = m0 + wm * 64 + mi * 16 + kg * 4;
                const int b = mb >> 10, sb = mb & 1023;
                u16x4 o;
#pragma unroll
                for (int r = 0; r < 4; ++r) o[r] = f2bf(acc[mi][nj][r] + bb);
                *(u16x4*)(vt + ((size_t)(b * 16 + head) * 64 + d) * 1024 + sb) = o;
            }
        }
    }
}

// ======================= attention (MFMA, FUSED passes) =======================
// 4096 blocks x 512 thr; block = one (bh, 16-row q-tile). XCD-swizzled.
// Both attention passes scored into sc1/sc2; ONE softmax phase normalizes
// both, writes a1 & a2 (NT), and fuses comb = C*(a1 - lam*a2) into sc1;
// ONE PV phase (V loaded once, 16 MFMAs instead of 32). 3 barriers not 6.
// (512,4): VGPR cap 128 -> no scratch spill.
__global__ __launch_bounds__(512, 4) void attn_kernel(
    const unsigned short* __restrict__ qk,   // 6 tensors [bh][1024][64]
    const unsigned short* __restrict__ vt,   // [bh][64][1024]
    const unsigned short* __restrict__ Cb,   // bf16 [1024][1024]
    const int* __restrict__ pad,
    const float* __restrict__ lam_p,
    float* __restrict__ out_a1, float* __restrict__ out_a2,
    float* __restrict__ merged)
{
    __shared__ __align__(16) unsigned short sc1[16][1032];   // 33 KB
    __shared__ __align__(16) unsigned short sc2[16][1032];   // 33 KB
    __shared__ __align__(16) float pmax1[16][8];
    __shared__ __align__(16) float pmax2[16][8];
    __shared__ __align__(16) f32x4 red[256];                 // 4 KB

    const int t  = threadIdx.x;
    const int w  = t >> 6;        // 0..7
    const int l  = t & 63;
    const int ln = l & 15;
    const int g  = l >> 4;
    const int kf = g * 8;

    const int flat = blockIdx.x;                       // 4096
    const int virt = (flat & 7) * 512 + (flat >> 3);   // XCD-contiguous bh
    const int bh = virt >> 6, b = bh >> 4, h = bh & 15;
    const int q0 = (virt & 63) * 16;
    const float lam = lam_p[0];

    const f32x4 Z = {0.f, 0.f, 0.f, 0.f};
    f32x4 ctx = Z;
    const int dt  = w & 3;         // d-tile (phase C)
    const int khf = w >> 2;        // k-half (phase C)

    // pad bitmask: bit j = key (w*128 + j*16 + ln) valid.
    uint32_t padm = 0;
#pragma unroll
    for (int j = 0; j < 8; ++j)
        padm |= (pad[b * S_LEN + w * 128 + j * 16 + ln] != 0 ? 1u : 0u) << j;

    const unsigned short* Q1h = qk + (size_t)0 * HSZ + (size_t)bh * 65536;
    const unsigned short* Q1l = qk + (size_t)1 * HSZ + (size_t)bh * 65536;
    const unsigned short* Q2h = qk + (size_t)2 * HSZ + (size_t)bh * 65536;
    const unsigned short* Q2l = qk + (size_t)3 * HSZ + (size_t)bh * 65536;
    const unsigned short* K1  = qk + (size_t)4 * HSZ + (size_t)bh * 65536;
    const unsigned short* K2  = qk + (size_t)5 * HSZ + (size_t)bh * 65536;

    const size_t qb = (size_t)(q0 + ln) * 64 + kf;
    const bf16x8 q1h0 = *(const bf16x8*)(Q1h + qb);
    const bf16x8 q1h1 = *(const bf16x8*)(Q1h + qb + 32);
    const bf16x8 q1l0 = *(const bf16x8*)(Q1l + qb);
    const bf16x8 q1l1 = *(const bf16x8*)(Q1l + qb + 32);
    const bf16x8 q2h0 = *(const bf16x8*)(Q2h + qb);
    const bf16x8 q2h1 = *(const bf16x8*)(Q2h + qb + 32);
    const bf16x8 q2l0 = *(const bf16x8*)(Q2l + qb);
    const bf16x8 q2l1 = *(const bf16x8*)(Q2l + qb + 32);

    // ---- phase A: raw scores for BOTH passes -> sc1/sc2 (f16), row maxes ----
    {
        f32x4 m1 = {-3.4e38f, -3.4e38f, -3.4e38f, -3.4e38f};
#pragma unroll 2
        for (int j = 0; j < 8; ++j) {
            const int key = w * 128 + j * 16 + ln;
            const size_t kb = (size_t)key * 64 + kf;
            const bf16x8 k0 = *(const bf16x8*)(K1 + kb);
            const bf16x8 k1 = *(const bf16x8*)(K1 + kb + 32);
            f32x4 a = Z;
            a = MFMA(q1h0, k0, a); a = MFMA(q1h1, k1, a);
            a = MFMA(q1l0, k0, a); a = MFMA(q1l1, k1, a);
            const bool ok = (padm >> j) & 1;
            const float mm = ok ? 0.125f : 0.0f;
            const float ma = ok ? 0.0f : -60000.0f;
#pragma unroll
            for (int r = 0; r < 4; ++r) {
                const float sv = a[r] * mm + ma;
                m1[r] = fmaxf(m1[r], sv);
                sc1[g * 4 + r][key] = f2h(sv);
            }
        }
#pragma unroll
        for (int off = 1; off < 16; off <<= 1)
#pragma unroll
            for (int r = 0; r < 4; ++r) m1[r] = fmaxf(m1[r], __shfl_xor(m1[r], off));
        if (ln == 0) {
#pragma unroll
            for (int r = 0; r < 4; ++r) pmax1[g * 4 + r][w] = m1[r];
        }
        f32x4 m2 = {-3.4e38f, -3.4e38f, -3.4e38f, -3.4e38f};
#pragma unroll 2
        for (int j = 0; j < 8; ++j) {
            const int key = w * 128 + j * 16 + ln;
            const size_t kb = (size_t)key * 64 + kf;
            const bf16x8 k0 = *(const bf16x8*)(K2 + kb);
            const bf16x8 k1 = *(const bf16x8*)(K2 + kb + 32);
            f32x4 a = Z;
            a = MFMA(q2h0, k0, a); a = MFMA(q2h1, k1, a);
            a = MFMA(q2l0, k0, a); a = MFMA(q2l1, k1, a);
            const bool ok = (padm >> j) & 1;
            const float mm = ok ? 0.125f : 0.0f;
            const float ma = ok ? 0.0f : -60000.0f;
#pragma unroll
            for (int r = 0; r < 4; ++r) {
                const float sv = a[r] * mm + ma;
                m2[r] = fmaxf(m2[r], sv);
                sc2[g * 4 + r][key] = f2h(sv);
            }
        }
#pragma unroll
        for (int off = 1; off < 16; off <<= 1)
#pragma unroll
            for (int r = 0; r < 4; ++r) m2[r] = fmaxf(m2[r], __shfl_xor(m2[r], off));
        if (ln == 0) {
#pragma unroll
            for (int r = 0; r < 4; ++r) pmax2[g * 4 + r][w] = m2[r];
        }
    }
    bar_lds();

    // ---- phase B: exp both (in place), rowsums, write a1/a2 (NT), fuse comb ----
    {
        const int row = t >> 5, ci = t & 31;
        float fm1 = -3.4e38f, fm2 = -3.4e38f;
#pragma unroll
        for (int wi = 0; wi < 8; ++wi) {
            fm1 = fmaxf(fm1, pmax1[row][wi]);
            fm2 = fmaxf(fm2, pmax2[row][wi]);
        }
        float sum1 = 0.f, sum2 = 0.f;
#pragma unroll 2
        for (int it = 0; it < 4; ++it) {
            const int c0 = ci * 8 + it * 256;
            const u16x8 xv1 = *(const u16x8*)&sc1[row][c0];
            const u16x8 xv2 = *(const u16x8*)&sc2[row][c0];
            u16x8 ev1, ev2;
#pragma unroll
            for (int i = 0; i < 8; ++i) {
                const float e1 = __expf(h2f(xv1[i]) - fm1);
                const float e2 = __expf(h2f(xv2[i]) - fm2);
                sum1 += e1; sum2 += e2;
                ev1[i] = f2h(e1); ev2[i] = f2h(e2);
            }
            *(u16x8*)&sc1[row][c0] = ev1;
            *(u16x8*)&sc2[row][c0] = ev2;
        }
#pragma unroll
        for (int off = 1; off < 32; off <<= 1) {
            sum1 += __shfl_xor(sum1, off);
            sum2 += __shfl_xor(sum2, off);
        }
        const float inv1 = 1.0f / sum1;
        const float inv2 = 1.0f / sum2;
        float* aout1 = out_a1 + ((size_t)bh * S_LEN + q0 + row) * S_LEN;
        float* aout2 = out_a2 + ((size_t)bh * S_LEN + q0 + row) * S_LEN;
        const unsigned short* Crow = Cb + (size_t)(q0 + row) * S_LEN;
#pragma unroll 2
        for (int it = 0; it < 4; ++it) {
            const int c0 = ci * 8 + it * 256;
            const u16x8 ev1 = *(const u16x8*)&sc1[row][c0];
            const u16x8 ev2 = *(const u16x8*)&sc2[row][c0];
            const u16x8 cv  = *(const u16x8*)&Crow[c0];
            float av1[8], av2[8];
#pragma unroll
            for (int i = 0; i < 8; ++i) {
                av1[i] = h2f(ev1[i]) * inv1;
                av2[i] = h2f(ev2[i]) * inv2;
            }
            f32x4 oa1 = {av1[0], av1[1], av1[2], av1[3]};
            f32x4 ob1 = {av1[4], av1[5], av1[6], av1[7]};
            f32x4 oa2 = {av2[0], av2[1], av2[2], av2[3]};
            f32x4 ob2 = {av2[4], av2[5], av2[6], av2[7]};
            __builtin_nontemporal_store(oa1, (f32x4*)&aout1[c0]);
            __builtin_nontemporal_store(ob1, (f32x4*)&aout1[c0 + 4]);
            __builtin_nontemporal_store(oa2, (f32x4*)&aout2[c0]);
            __builtin_nontemporal_store(ob2, (f32x4*)&aout2[c0 + 4]);
            u16x8 cw;
#pragma unroll
            for (int i = 0; i < 8; ++i)
                cw[i] = f2bf(bf2f(cv[i]) * (av1[i] - lam * av2[i]));
            *(u16x8*)&sc1[row][c0] = cw;
        }
    }
    bar_lds();

    // ---- phase C: single PV over fused comb; wave = (dt, khf) ----
    {
        const unsigned short* vtb = vt + (size_t)bh * 65536
                                       + (size_t)(dt * 16 + ln) * S_LEN + kf;
#pragma unroll 4
        for (int ks = 0; ks < 16; ++ks) {
            const int kk = khf * 16 + ks;
            const bf16x8 A0 = *(const bf16x8*)&sc1[ln][kk * 32 + kf];
            const bf16x8 Bv = *(const bf16x8*)(vtb + kk * 32);
            ctx = MFMA(A0, Bv, ctx);
        }
    }

    // ---- cross-khf reduction + merged store ----
    __syncthreads();
    if (khf == 1) red[dt * 64 + l] = ctx;
    __syncthreads();
    if (khf == 0) {
        ctx += red[dt * 64 + l];
        const int col = h * DH + dt * 16 + ln;
#pragma unroll
        for (int r = 0; r < 4; ++r)
            merged[(size_t)(b * S_LEN + q0 + g * 4 + r) * 1024 + col] = ctx[r];
    }
}

// ======================= group-norm stats =======================
__global__ __launch_bounds__(256) void stats_kernel(
    const float* __restrict__ merged, float* __restrict__ stats)
{
    const int g = blockIdx.x;
    const int b = g >> 4, h = g & 15;
    const int t = threadIdx.x;
    float sum = 0.f, sq = 0.f;
    for (int i = t; i < 65536; i += 256) {
        const int s = i >> 6, d = i & 63;
        const float v = merged[((size_t)(b * S_LEN + s)) * 1024 + h * DH + d];
        sum += v; sq += v * v;
    }
#pragma unroll
    for (int off = 32; off > 0; off >>= 1) {
        sum += __shfl_xor(sum, off);
        sq  += __shfl_xor(sq, off);
    }
    __shared__ float rs[4], rq[4];
    const int wid = t >> 6;
    if ((t & 63) == 0) { rs[wid] = sum; rq[wid] = sq; }
    __syncthreads();
    if (t == 0) {
        const float S = rs[0] + rs[1] + rs[2] + rs[3];
        const float Q = rq[0] + rq[1] + rq[2] + rq[3];
        const float mean = S * (1.0f / 65536.0f);
        const float var  = Q * (1.0f / 65536.0f) - mean * mean;
        stats[2*g]   = mean;
        stats[2*g+1] = rsqrtf(var + 1e-5f);
    }
}

// ======================= groupnorm apply -> bf16 =======================
__global__ __launch_bounds__(256) void norm_conv_kernel(
    const float* __restrict__ merged, const float* __restrict__ stats,
    const float* __restrict__ gw, const float* __restrict__ gb,
    unsigned short* __restrict__ normed)
{
    const int idx = blockIdx.x * 256 + threadIdx.x;   // 524288
    const int m = idx >> 7;
    const int col8 = (idx & 127) * 8;
    const int b = m >> 10, h = col8 >> 6;
    const float mean = stats[2 * (b * 16 + h)];
    const float inv  = stats[2 * (b * 16 + h) + 1];
    float4 v0 = *(const float4*)&merged[(size_t)m * 1024 + col8];
    float4 v1 = *(const float4*)&merged[(size_t)m * 1024 + col8 + 4];
    float4 w0 = *(const float4*)&gw[col8];
    float4 w1 = *(const float4*)&gw[col8 + 4];
    float4 g0 = *(const float4*)&gb[col8];
    float4 g1 = *(const float4*)&gb[col8 + 4];
    float v[8] = {v0.x, v0.y, v0.z, v0.w, v1.x, v1.y, v1.z, v1.w};
    float wv[8] = {w0.x, w0.y, w0.z, w0.w, w1.x, w1.y, w1.z, w1.w};
    float gv[8] = {g0.x, g0.y, g0.z, g0.w, g1.x, g1.y, g1.z, g1.w};
    u16x8 o;
#pragma unroll
    for (int j = 0; j < 8; ++j)
        o[j] = f2bf(((v[j] - mean) * inv * wv[j] + gv[j]) * 0.2f);
    *(u16x8*)&normed[(size_t)m * 1024 + col8] = o;
}

// ======================= output GEMM (MFMA, single bf16) =======================
__global__ __launch_bounds__(256) void out_mfma_kernel(
    const unsigned short* __restrict__ An, const unsigned short* __restrict__ Wo_bf,
    const float* __restrict__ bo, float* __restrict__ out)
{
    __shared__ __align__(16) unsigned short As[128 * 64];
    __shared__ __align__(16) unsigned short Bs[128 * 64];

    const int t   = threadIdx.x;
    const int bid = blockIdx.x;                 // 256
    const int swz = (bid & 7) * 32 + (bid >> 3);
    const int n_idx = swz & 7, m_idx = swz >> 3;
    const int m0 = m_idx * 128, n0 = n_idx * 128;
    const int w = t >> 6, l = t & 63, ln = l & 15, kg = l >> 4;
    const int wm = w >> 1, wn = w & 1;

    f32x4 acc[4][4];
#pragma unroll
    for (int i = 0; i < 4; ++i)
#pragma unroll
        for (int j = 0; j < 4; ++j) acc[i][j] = (f32x4){0.f, 0.f, 0.f, 0.f};

    for (int k0 = 0; k0 < 1024; k0 += 64) {
        __syncthreads();
#pragma unroll
        for (int i = 0; i < 4; ++i) {
            const int e   = t + i * 256;
            const int row = e >> 3, cg = e & 7;
            const int off = (row * 128 + cg * 16) ^ ((row & 7) << 4);
            *(bf16x8*)((char*)As + off) = *(const bf16x8*)(An + (size_t)(m0 + row) * 1024 + k0 + cg * 8);
            *(bf16x8*)((char*)Bs + off) = *(const bf16x8*)(Wo_bf + (size_t)(n0 + row) * 1024 + k0 + cg * 8);
        }
        __syncthreads();
#pragma unroll
        for (int ks = 0; ks < 2; ++ks) {
            bf16x8 bfrag[4];
#pragma unroll
            for (int nj = 0; nj < 4; ++nj) {
                const int row = wn * 64 + nj * 16 + ln;
                const int off = (row * 128 + ks * 64 + kg * 16) ^ ((row & 7) << 4);
                bfrag[nj] = *(const bf16x8*)((const char*)Bs + off);
            }
#pragma unroll
            for (int mi = 0; mi < 4; ++mi) {
                const int row = wm * 64 + mi * 16 + ln;
                const int off = (row * 128 + ks * 64 + kg * 16) ^ ((row & 7) << 4);
                bf16x8 af = *(const bf16x8*)((const char*)As + off);
#pragma unroll
                for (int nj = 0; nj < 4; ++nj)
                    acc[mi][nj] = MFMA(af, bfrag[nj], acc[mi][nj]);
            }
        }
    }

#pragma unroll
    for (int mi = 0; mi < 4; ++mi) {
#pragma unroll
        for (int nj = 0; nj < 4; ++nj) {
            const int n = n0 + wn * 64 + nj * 16 + ln;
            const float bb = bo[n];
            const int mb = m0 + wm * 64 + mi * 16 + kg * 4;
#pragma unroll
            for (int r = 0; r < 4; ++r)
                out[(size_t)(mb + r) * 1024 + n] = acc[mi][nj][r] + bb;
        }
    }
}

// ======================= launcher =======================
extern "C" void kernel_launch(void* const* d_in, const int* in_sizes, int n_in,
                              void* d_out, int out_size, void* d_ws, size_t ws_size,
                              hipStream_t stream)
{
    const float* x   = (const float*)d_in[0];
    const float* lam = (const float*)d_in[1];
    const float* C   = (const float*)d_in[2];
    const int*   pad = (const int*)  d_in[3];
    const float* wq  = (const float*)d_in[4];
    const float* bq  = (const float*)d_in[5];
    const float* wk  = (const float*)d_in[6];
    const float* bk  = (const float*)d_in[7];
    const float* wv  = (const float*)d_in[8];
    const float* bv  = (const float*)d_in[9];
    const float* wo  = (const float*)d_in[10];
    const float* bo  = (const float*)d_in[11];
    const float* gw  = (const float*)d_in[12];
    const float* gb  = (const float*)d_in[13];

    float* out = (float*)d_out;
    float* a1  = out + 4194304;
    float* a2  = a1 + 67108864;

    unsigned short* xh   = (unsigned short*)d_ws;              // HSZ bf16 (dead after proj)
    unsigned short* xl   = xh + HSZ;                           // HSZ bf16 (dead after proj)
    unsigned short* qk   = xl + HSZ;                           // 6*HSZ bf16
    unsigned short* vt   = qk + 6 * HSZ;                       // HSZ bf16
    unsigned short* Wcat = vt + HSZ;                           // 6144*1024 bf16
    float* merged        = (float*)(Wcat + 6144ull * 1024);    // HSZ fp32
    float* stats         = merged + HSZ;                       // 128 fp32
    unsigned short* normed = (unsigned short*)(stats + 128);   // HSZ bf16
    unsigned short* Cb   = xh;                                 // alias: 1M bf16 in dead xh region

    conv_x_kernel<<<2048, 256, 0, stream>>>(x, xh, xl);
    conv_w_kernel<<<3072, 256, 0, stream>>>(wq, wk, wv, wo, Wcat);
    proj_mfma_kernel<<<1280, 256, 0, stream>>>(xh, xl, Wcat, bq, bk, bv, qk, vt);
    conv_c_kernel<<<512, 256, 0, stream>>>(C, Cb);
    attn_kernel<<<4096, 512, 0, stream>>>(qk, vt, Cb, pad, lam, a1, a2, merged);
    stats_kernel<<<64, 256, 0, stream>>>(merged, stats);
    norm_conv_kernel<<<2048, 256, 0, stream>>>(merged, stats, gw, gb, normed);
    out_mfma_kernel<<<256, 256, 0, stream>>>(normed, Wcat + 5120ull * 1024, bo, out);
}